// Round 1
// baseline (529.302 us; speedup 1.0000x reference)
//
#include <hip/hip_runtime.h>

// Problem constants (HyperGCNConv: N=100000, M=50000, K=8, DIN=DOUT=128)
#define NV 100000
#define ME 50000
#define DD 128
__device__ __constant__ float WMED_DUMMY; // (unused; keep constants as literals)
constexpr float WMED = 1.0f / 13.0f;      // 1/(2K-3), K=8

// ---------------- K1: Y = X @ W + b (fp32, vector ALU) ----------------
// block = 128 threads (thread j = output column j), 16 rows per block.
// W staged in LDS in two 64-row halves (32KB), X tile 16x128 (8KB).
__global__ __launch_bounds__(128) void k_gemm(const float* __restrict__ X,
                                              const float* __restrict__ W,
                                              const float* __restrict__ bias,
                                              float* __restrict__ Y) {
    __shared__ float sW[64 * 128];
    __shared__ float sX[16 * 128];
    const int j = threadIdx.x;            // 0..127
    const int row0 = blockIdx.x * 16;

    #pragma unroll
    for (int r = 0; r < 16; ++r)
        sX[r * 128 + j] = X[(long)(row0 + r) * 128 + j];

    float acc[16];
    #pragma unroll
    for (int r = 0; r < 16; ++r) acc[r] = 0.0f;

    for (int half = 0; half < 2; ++half) {
        __syncthreads();
        #pragma unroll
        for (int kk = 0; kk < 64; ++kk)
            sW[kk * 128 + j] = W[(half * 64 + kk) * 128 + j];
        __syncthreads();
        #pragma unroll
        for (int k4 = 0; k4 < 16; ++k4) {
            const float w0 = sW[(k4 * 4 + 0) * 128 + j];
            const float w1 = sW[(k4 * 4 + 1) * 128 + j];
            const float w2 = sW[(k4 * 4 + 2) * 128 + j];
            const float w3 = sW[(k4 * 4 + 3) * 128 + j];
            #pragma unroll
            for (int r = 0; r < 16; ++r) {
                const float4 xq = *(const float4*)(sX + r * 128 + half * 64 + k4 * 4);
                acc[r] = fmaf(xq.x, w0, acc[r]);
                acc[r] = fmaf(xq.y, w1, acc[r]);
                acc[r] = fmaf(xq.z, w2, acc[r]);
                acc[r] = fmaf(xq.w, w3, acc[r]);
            }
        }
    }
    const float bj = bias[j];
    #pragma unroll
    for (int r = 0; r < 16; ++r)
        Y[(long)(row0 + r) * 128 + j] = acc[r] + bj;
}

// ---------------- K2a: deg = 1.0 ----------------
__global__ __launch_bounds__(256) void k_initdeg(float* __restrict__ deg) {
    const int i = blockIdx.x * 256 + threadIdx.x;
    if (i < NV) deg[i] = 1.0f;
}

// ---------------- K2: per-hyperedge argmax pair + deg atomics ----------------
// one wave per hyperedge; 4 waves per block.
__global__ __launch_bounds__(256) void k_edge(const float* __restrict__ Y,
                                              const int* __restrict__ vertex,
                                              float* __restrict__ deg,
                                              int* __restrict__ uvpos) {
    __shared__ float sF[4][8 * 132];   // pad row stride 132 -> conflict-free dots
    const int wid = threadIdx.x >> 6;
    const int lane = threadIdx.x & 63;
    const int m = blockIdx.x * 4 + wid;
    float* F = sF[wid];

    int verts[8];
    #pragma unroll
    for (int p = 0; p < 8; ++p) verts[p] = vertex[m * 8 + p];

    // stage 8 feature rows (float2 per lane per row)
    #pragma unroll
    for (int p = 0; p < 8; ++p) {
        const float2 v = *(const float2*)(Y + (long)verts[p] * 128 + lane * 2);
        *(float2*)(F + p * 132 + lane * 2) = v;
    }
    __syncthreads();

    // lane -> pair (k,l); flat index == lane (row-major K*K) matches np.argmax order
    const int k = lane >> 3, l = lane & 7;
    float acc = 0.0f;
    const float4* ra = (const float4*)(F + k * 132);
    const float4* rb = (const float4*)(F + l * 132);
    #pragma unroll
    for (int d4 = 0; d4 < 32; ++d4) {
        const float4 a = ra[d4], b = rb[d4];
        acc = fmaf(a.x, b.x, acc);
        acc = fmaf(a.y, b.y, acc);
        acc = fmaf(a.z, b.z, acc);
        acc = fmaf(a.w, b.w, acc);
    }
    // d2 = sq[k] + sq[l] - 2*dot  (diagonal lanes hold sq)
    const float sqk = __shfl(acc, k * 9);
    const float sql = __shfl(acc, l * 9);
    float v = sqk + sql - 2.0f * acc;
    int idx = lane;
    // argmax with first-occurrence (min flat index) tie-break
    #pragma unroll
    for (int off = 32; off >= 1; off >>= 1) {
        const float ov = __shfl_xor(v, off);
        const int oi = __shfl_xor(idx, off);
        if (ov > v || (ov == v && oi < idx)) { v = ov; idx = oi; }
    }
    const int ui = idx >> 3, vi = idx & 7;
    if (lane == 0) uvpos[m] = idx;

    // deg updates: deg[u] += w + sum(medw); deg[v] += w + sum(medw);
    // deg[verts[p]] += 2*medw[p]   (exactly the reference src/dst decomposition)
    float summed = 0.0f;
    #pragma unroll
    for (int p = 0; p < 8; ++p) summed += (p != ui && p != vi) ? WMED : 0.0f;
    if (lane < 8) {
        const int p = lane;
        if (p != ui && p != vi) atomicAdd(deg + verts[p], 2.0f * WMED);
    } else if (lane == 8) {
        atomicAdd(deg + verts[ui], WMED + summed);
    } else if (lane == 9) {
        atomicAdd(deg + verts[vi], WMED + summed);
    }
}

// ---------------- K3: dinv = rsqrt(deg); Xs = Y*dinv (in place); out = Xs ----
__global__ __launch_bounds__(256) void k_xs(float* __restrict__ Y,
                                            const float* __restrict__ deg,
                                            float* __restrict__ dinv,
                                            float* __restrict__ out) {
    const long t = (long)blockIdx.x * 256 + threadIdx.x;   // over N*32 float4s
    const int i = (int)(t >> 5);
    const float di = rsqrtf(deg[i]);
    if ((t & 31) == 0) dinv[i] = di;
    float4 y = ((const float4*)Y)[t];
    y.x *= di; y.y *= di; y.z *= di; y.w *= di;
    ((float4*)Y)[t] = y;
    ((float4*)out)[t] = y;
}

// ---------------- K4: scatter smoothing contributions ----------------
// one wave per hyperedge; lane handles dims (lane, lane+64).
__global__ __launch_bounds__(256) void k_scatter(const float* __restrict__ Xs,
                                                 const int* __restrict__ vertex,
                                                 const int* __restrict__ uvpos,
                                                 float* __restrict__ out) {
    const int wid = threadIdx.x >> 6;
    const int lane = threadIdx.x & 63;
    const int m = blockIdx.x * 4 + wid;

    int verts[8];
    #pragma unroll
    for (int p = 0; p < 8; ++p) verts[p] = vertex[m * 8 + p];
    const int idx = uvpos[m];
    const int ui = idx >> 3, vi = idx & 7;
    const int d0 = lane, d1 = lane + 64;

    float S0 = 0.f, S1 = 0.f, Xu0 = 0.f, Xu1 = 0.f, Xv0 = 0.f, Xv1 = 0.f;
    #pragma unroll
    for (int p = 0; p < 8; ++p) {
        const float* row = Xs + (long)verts[p] * 128;
        const float a = row[d0];
        const float c = row[d1];
        const bool isu = (p == ui), isv = (p == vi);
        if (isu) { Xu0 = a; Xu1 = c; }
        if (isv) { Xv0 = a; Xv1 = c; }
        if (!isu && !isv) { S0 += a; S1 += c; }
    }
    S0 *= WMED; S1 *= WMED;

    // out[u] += w*Xs[v] + S ; out[v] += w*Xs[u] + S
    atomicAdd(out + (long)verts[ui] * 128 + d0, fmaf(WMED, Xv0, S0));
    atomicAdd(out + (long)verts[ui] * 128 + d1, fmaf(WMED, Xv1, S1));
    atomicAdd(out + (long)verts[vi] * 128 + d0, fmaf(WMED, Xu0, S0));
    atomicAdd(out + (long)verts[vi] * 128 + d1, fmaf(WMED, Xu1, S1));
    // mediators: out[m_p] += w*(Xs[u]+Xs[v])
    const float mu0 = WMED * (Xu0 + Xv0);
    const float mu1 = WMED * (Xu1 + Xv1);
    #pragma unroll
    for (int p = 0; p < 8; ++p) {
        if (p != ui && p != vi) {
            atomicAdd(out + (long)verts[p] * 128 + d0, mu0);
            atomicAdd(out + (long)verts[p] * 128 + d1, mu1);
        }
    }
}

// ---------------- K5: out = relu(out * dinv) ----------------
__global__ __launch_bounds__(256) void k_final(float* __restrict__ out,
                                               const float* __restrict__ dinv) {
    const long t = (long)blockIdx.x * 256 + threadIdx.x;   // over N*32 float4s
    const int i = (int)(t >> 5);
    const float di = dinv[i];
    float4 o = ((float4*)out)[t];
    o.x = fmaxf(o.x * di, 0.0f);
    o.y = fmaxf(o.y * di, 0.0f);
    o.z = fmaxf(o.z * di, 0.0f);
    o.w = fmaxf(o.w * di, 0.0f);
    ((float4*)out)[t] = o;
}

extern "C" void kernel_launch(void* const* d_in, const int* in_sizes, int n_in,
                              void* d_out, int out_size, void* d_ws, size_t ws_size,
                              hipStream_t stream) {
    const float* X      = (const float*)d_in[0];   // [N,128]
    const int*   vertex = (const int*)d_in[1];     // [M*8]
    // d_in[2] = edges (repeat(arange(M),8)) -- structure known, unused
    const float* W      = (const float*)d_in[3];   // [128,128]
    const float* bias   = (const float*)d_in[4];   // [128]
    float* out = (float*)d_out;                    // [N,128]

    // workspace layout: Y[N*128] | deg[N] | dinv[N] | uvpos[M]  (~52.2 MB)
    float* Y    = (float*)d_ws;
    float* deg  = Y + (long)NV * 128;
    float* dinv = deg + NV;
    int*   uvpos = (int*)(dinv + NV);

    k_gemm   <<<NV / 16, 128, 0, stream>>>(X, W, bias, Y);         // 6250 blocks
    k_initdeg<<<(NV + 255) / 256, 256, 0, stream>>>(deg);
    k_edge   <<<ME / 4, 256, 0, stream>>>(Y, vertex, deg, uvpos);  // 12500 blocks
    k_xs     <<<(NV * 32) / 256, 256, 0, stream>>>(Y, deg, dinv, out);
    k_scatter<<<ME / 4, 256, 0, stream>>>(Y, vertex, uvpos, out);
    k_final  <<<(NV * 32) / 256, 256, 0, stream>>>(out, dinv);
}

// Round 2
// 384.281 us; speedup vs baseline: 1.3774x; 1.3774x over previous
//
#include <hip/hip_runtime.h>

// Problem constants (HyperGCNConv: N=100000, M=50000, K=8, DIN=DOUT=128)
#define NV 100000
#define ME 50000
constexpr float WMED = 1.0f / 13.0f;      // 1/(2K-3), K=8

// ---------------- K1: Y = X @ W + b (fp32, vector ALU) ----------------
// Register-blocked: block 256 threads, tile 128 rows x 128 cols.
// Thread (cg = t&31, rg = t>>5) computes rows [16rg,16rg+16) x cols [4cg,4cg+4).
// K staged in two halves of 64. Per 4-k: 4 per-lane b128 W reads +
// 16 half-wave-broadcast b128 X reads feed 256 FMAs (LDS:VALU ~1:4).
__global__ __launch_bounds__(256) void k_gemm(const float* __restrict__ X,
                                              const float* __restrict__ W,
                                              const float* __restrict__ bias,
                                              float* __restrict__ Y) {
    __shared__ float sX[128 * 68];   // [row][k] , k-half, stride 68 (b128-aligned pad)
    __shared__ float sW[64 * 128];   // [k][col]
    const int t = threadIdx.x;
    const int cg = t & 31;           // col group -> cols 4cg..4cg+3
    const int rg = t >> 5;           // row group -> rows 16rg..16rg+15
    const int row0 = blockIdx.x * 128;

    float acc[16][4];
    #pragma unroll
    for (int i = 0; i < 16; ++i) {
        acc[i][0] = 0.f; acc[i][1] = 0.f; acc[i][2] = 0.f; acc[i][3] = 0.f;
    }

    for (int h = 0; h < 2; ++h) {
        __syncthreads();
        // stage X: 128 rows x 64 k = 2048 float4, 8 per thread (coalesced)
        #pragma unroll
        for (int i = 0; i < 8; ++i) {
            const int idx = t + i * 256;
            const int row = idx >> 4;          // 16 float4 per row
            const int kq  = idx & 15;
            int gr = row0 + row; if (gr > NV - 1) gr = NV - 1;   // clamp tail
            const float4 v = *(const float4*)(X + (long)gr * 128 + h * 64 + kq * 4);
            *(float4*)(sX + row * 68 + kq * 4) = v;
        }
        // stage W k-half: 64 x 128 = 2048 float4, 8 per thread (coalesced)
        #pragma unroll
        for (int i = 0; i < 8; ++i) {
            const int idx = t + i * 256;
            const int k  = idx >> 5;           // 32 float4 per k row
            const int cq = idx & 31;
            const float4 v = *(const float4*)(W + (long)(h * 64 + k) * 128 + cq * 4);
            *(float4*)(sW + k * 128 + cq * 4) = v;
        }
        __syncthreads();

        #pragma unroll 4
        for (int k4 = 0; k4 < 16; ++k4) {
            const float4 w0 = *(const float4*)(sW + (k4 * 4 + 0) * 128 + cg * 4);
            const float4 w1 = *(const float4*)(sW + (k4 * 4 + 1) * 128 + cg * 4);
            const float4 w2 = *(const float4*)(sW + (k4 * 4 + 2) * 128 + cg * 4);
            const float4 w3 = *(const float4*)(sW + (k4 * 4 + 3) * 128 + cg * 4);
            #pragma unroll
            for (int i = 0; i < 16; ++i) {
                const float4 xq = *(const float4*)(sX + (rg * 16 + i) * 68 + k4 * 4);
                acc[i][0] = fmaf(xq.x, w0.x, acc[i][0]);
                acc[i][1] = fmaf(xq.x, w0.y, acc[i][1]);
                acc[i][2] = fmaf(xq.x, w0.z, acc[i][2]);
                acc[i][3] = fmaf(xq.x, w0.w, acc[i][3]);
                acc[i][0] = fmaf(xq.y, w1.x, acc[i][0]);
                acc[i][1] = fmaf(xq.y, w1.y, acc[i][1]);
                acc[i][2] = fmaf(xq.y, w1.z, acc[i][2]);
                acc[i][3] = fmaf(xq.y, w1.w, acc[i][3]);
                acc[i][0] = fmaf(xq.z, w2.x, acc[i][0]);
                acc[i][1] = fmaf(xq.z, w2.y, acc[i][1]);
                acc[i][2] = fmaf(xq.z, w2.z, acc[i][2]);
                acc[i][3] = fmaf(xq.z, w2.w, acc[i][3]);
                acc[i][0] = fmaf(xq.w, w3.x, acc[i][0]);
                acc[i][1] = fmaf(xq.w, w3.y, acc[i][1]);
                acc[i][2] = fmaf(xq.w, w3.z, acc[i][2]);
                acc[i][3] = fmaf(xq.w, w3.w, acc[i][3]);
            }
        }
    }

    const float4 bj = *(const float4*)(bias + cg * 4);
    #pragma unroll
    for (int i = 0; i < 16; ++i) {
        const int gr = row0 + rg * 16 + i;
        if (gr < NV) {
            float4 o;
            o.x = acc[i][0] + bj.x; o.y = acc[i][1] + bj.y;
            o.z = acc[i][2] + bj.z; o.w = acc[i][3] + bj.w;
            *(float4*)(Y + (long)gr * 128 + cg * 4) = o;
        }
    }
}

// ---------------- K2a: deg = 1.0 ----------------
__global__ __launch_bounds__(256) void k_initdeg(float* __restrict__ deg) {
    const int i = blockIdx.x * 256 + threadIdx.x;
    if (i < NV) deg[i] = 1.0f;
}

// ---------------- K2: per-hyperedge argmax pair + deg atomics ----------------
// one wave per hyperedge; 4 waves per block.
__global__ __launch_bounds__(256) void k_edge(const float* __restrict__ Y,
                                              const int* __restrict__ vertex,
                                              float* __restrict__ deg,
                                              int* __restrict__ uvpos) {
    __shared__ float sF[4][8 * 132];   // pad row stride 132 -> conflict-free dots
    const int wid = threadIdx.x >> 6;
    const int lane = threadIdx.x & 63;
    const int m = blockIdx.x * 4 + wid;
    float* F = sF[wid];

    int verts[8];
    #pragma unroll
    for (int p = 0; p < 8; ++p) verts[p] = vertex[m * 8 + p];

    // stage 8 feature rows (float2 per lane per row)
    #pragma unroll
    for (int p = 0; p < 8; ++p) {
        const float2 v = *(const float2*)(Y + (long)verts[p] * 128 + lane * 2);
        *(float2*)(F + p * 132 + lane * 2) = v;
    }
    __syncthreads();

    // lane -> pair (k,l); flat index == lane (row-major K*K) matches np.argmax order
    const int k = lane >> 3, l = lane & 7;
    float acc = 0.0f;
    const float4* ra = (const float4*)(F + k * 132);
    const float4* rb = (const float4*)(F + l * 132);
    #pragma unroll
    for (int d4 = 0; d4 < 32; ++d4) {
        const float4 a = ra[d4], b = rb[d4];
        acc = fmaf(a.x, b.x, acc);
        acc = fmaf(a.y, b.y, acc);
        acc = fmaf(a.z, b.z, acc);
        acc = fmaf(a.w, b.w, acc);
    }
    // d2 = sq[k] + sq[l] - 2*dot  (diagonal lanes hold sq)
    const float sqk = __shfl(acc, k * 9);
    const float sql = __shfl(acc, l * 9);
    float v = sqk + sql - 2.0f * acc;
    int idx = lane;
    // argmax with first-occurrence (min flat index) tie-break
    #pragma unroll
    for (int off = 32; off >= 1; off >>= 1) {
        const float ov = __shfl_xor(v, off);
        const int oi = __shfl_xor(idx, off);
        if (ov > v || (ov == v && oi < idx)) { v = ov; idx = oi; }
    }
    const int ui = idx >> 3, vi = idx & 7;
    if (lane == 0) uvpos[m] = idx;

    // deg updates: deg[u] += w + sum(medw); deg[v] += w + sum(medw);
    // deg[verts[p]] += 2*medw[p]   (exactly the reference src/dst decomposition)
    float summed = 0.0f;
    #pragma unroll
    for (int p = 0; p < 8; ++p) summed += (p != ui && p != vi) ? WMED : 0.0f;
    if (lane < 8) {
        const int p = lane;
        if (p != ui && p != vi) atomicAdd(deg + verts[p], 2.0f * WMED);
    } else if (lane == 8) {
        atomicAdd(deg + verts[ui], WMED + summed);
    } else if (lane == 9) {
        atomicAdd(deg + verts[vi], WMED + summed);
    }
}

// ---------------- K3: dinv = rsqrt(deg); Xs = Y*dinv (in place); out = Xs ----
__global__ __launch_bounds__(256) void k_xs(float* __restrict__ Y,
                                            const float* __restrict__ deg,
                                            float* __restrict__ dinv,
                                            float* __restrict__ out) {
    const long t = (long)blockIdx.x * 256 + threadIdx.x;   // over N*32 float4s
    const int i = (int)(t >> 5);
    const float di = rsqrtf(deg[i]);
    if ((t & 31) == 0) dinv[i] = di;
    float4 y = ((const float4*)Y)[t];
    y.x *= di; y.y *= di; y.z *= di; y.w *= di;
    ((float4*)Y)[t] = y;
    ((float4*)out)[t] = y;
}

// ---------------- K4: scatter smoothing contributions ----------------
// one wave per hyperedge; lane handles dims (lane, lane+64).
__global__ __launch_bounds__(256) void k_scatter(const float* __restrict__ Xs,
                                                 const int* __restrict__ vertex,
                                                 const int* __restrict__ uvpos,
                                                 float* __restrict__ out) {
    const int wid = threadIdx.x >> 6;
    const int lane = threadIdx.x & 63;
    const int m = blockIdx.x * 4 + wid;

    int verts[8];
    #pragma unroll
    for (int p = 0; p < 8; ++p) verts[p] = vertex[m * 8 + p];
    const int idx = uvpos[m];
    const int ui = idx >> 3, vi = idx & 7;
    const int d0 = lane, d1 = lane + 64;

    float S0 = 0.f, S1 = 0.f, Xu0 = 0.f, Xu1 = 0.f, Xv0 = 0.f, Xv1 = 0.f;
    #pragma unroll
    for (int p = 0; p < 8; ++p) {
        const float* row = Xs + (long)verts[p] * 128;
        const float a = row[d0];
        const float c = row[d1];
        const bool isu = (p == ui), isv = (p == vi);
        if (isu) { Xu0 = a; Xu1 = c; }
        if (isv) { Xv0 = a; Xv1 = c; }
        if (!isu && !isv) { S0 += a; S1 += c; }
    }
    S0 *= WMED; S1 *= WMED;

    // out[u] += w*Xs[v] + S ; out[v] += w*Xs[u] + S
    atomicAdd(out + (long)verts[ui] * 128 + d0, fmaf(WMED, Xv0, S0));
    atomicAdd(out + (long)verts[ui] * 128 + d1, fmaf(WMED, Xv1, S1));
    atomicAdd(out + (long)verts[vi] * 128 + d0, fmaf(WMED, Xu0, S0));
    atomicAdd(out + (long)verts[vi] * 128 + d1, fmaf(WMED, Xu1, S1));
    // mediators: out[m_p] += w*(Xs[u]+Xs[v])
    const float mu0 = WMED * (Xu0 + Xv0);
    const float mu1 = WMED * (Xu1 + Xv1);
    #pragma unroll
    for (int p = 0; p < 8; ++p) {
        if (p != ui && p != vi) {
            atomicAdd(out + (long)verts[p] * 128 + d0, mu0);
            atomicAdd(out + (long)verts[p] * 128 + d1, mu1);
        }
    }
}

// ---------------- K5: out = relu(out * dinv) ----------------
__global__ __launch_bounds__(256) void k_final(float* __restrict__ out,
                                               const float* __restrict__ dinv) {
    const long t = (long)blockIdx.x * 256 + threadIdx.x;   // over N*32 float4s
    const int i = (int)(t >> 5);
    const float di = dinv[i];
    float4 o = ((float4*)out)[t];
    o.x = fmaxf(o.x * di, 0.0f);
    o.y = fmaxf(o.y * di, 0.0f);
    o.z = fmaxf(o.z * di, 0.0f);
    o.w = fmaxf(o.w * di, 0.0f);
    ((float4*)out)[t] = o;
}

extern "C" void kernel_launch(void* const* d_in, const int* in_sizes, int n_in,
                              void* d_out, int out_size, void* d_ws, size_t ws_size,
                              hipStream_t stream) {
    const float* X      = (const float*)d_in[0];   // [N,128]
    const int*   vertex = (const int*)d_in[1];     // [M*8]
    // d_in[2] = edges (repeat(arange(M),8)) -- structure known, unused
    const float* W      = (const float*)d_in[3];   // [128,128]
    const float* bias   = (const float*)d_in[4];   // [128]
    float* out = (float*)d_out;                    // [N,128]

    // workspace layout: Y[N*128] | deg[N] | dinv[N] | uvpos[M]  (~52.2 MB)
    float* Y    = (float*)d_ws;
    float* deg  = Y + (long)NV * 128;
    float* dinv = deg + NV;
    int*   uvpos = (int*)(dinv + NV);

    k_gemm   <<<(NV + 127) / 128, 256, 0, stream>>>(X, W, bias, Y);  // 782 blocks
    k_initdeg<<<(NV + 255) / 256, 256, 0, stream>>>(deg);
    k_edge   <<<ME / 4, 256, 0, stream>>>(Y, vertex, deg, uvpos);    // 12500 blocks
    k_xs     <<<(NV * 32) / 256, 256, 0, stream>>>(Y, deg, dinv, out);
    k_scatter<<<ME / 4, 256, 0, stream>>>(Y, vertex, uvpos, out);
    k_final  <<<(NV * 32) / 256, 256, 0, stream>>>(out, dinv);
}